// Round 13
// baseline (126.337 us; speedup 1.0000x reference)
//
#include <hip/hip_runtime.h>

// Problem constants (match reference)
#define B_   16
#define N_   65536
#define G_   64
#define M_   (N_ + G_)       // 65600 rois per batch
#define HALF_ 32800          // M_/2: each iou thread handles i and i+HALF_
#define R_   128             // ROIS_PER_IMAGE
#define FGP  32              // FG_PER_IMAGE
#define NB_  16384           // buckets over u_perm in [0,1): lambda ~= 3.7 bg
#define NCH_ 32              // coarse chunks per row
#define CHUNK_ (NB_ / NCH_)  // 512
#define NROW_ 32             // (batch, class) rows
#define FW_  (NB_ / 32)      // flag words per row = 512
#define TPB_  256

// ---------------------------------------------------------------------------
// K0: zero hist; GT table (poisoned gt_zero rows) + jmax.
// ---------------------------------------------------------------------------
__global__ void prep_kernel(const float* __restrict__ gt_boxes,
                            int*    __restrict__ hist,
                            float4* __restrict__ gt4,
                            float*  __restrict__ garea,
                            int*    __restrict__ jmax)
{
    const int gid = blockIdx.x * blockDim.x + threadIdx.x;
    for (int idx = gid; idx < NROW_ * NB_; idx += gridDim.x * blockDim.x) hist[idx] = 0;
    if (gid < B_ * G_) {
        int b = gid >> 6, j = gid & 63;
        const float* g = gt_boxes + gid * 6;
        float x1 = g[0], y1 = g[1], x2 = g[2], y2 = g[3];
        float gw = x2 - x1 + 1.0f, gh = y2 - y1 + 1.0f;
        bool gz = (gw == 1.0f) && (gh == 1.0f);
        gt4[gid] = gz ? make_float4(3.0e8f, 3.0e8f, -3.0e8f, -3.0e8f)
                      : make_float4(x1, y1, x2, y2);
        garea[gid] = gw * gh;                     // == 1.0 for gz rows
        unsigned long long alive = __ballot(!gz); // lane == j
        if (j == 0) { int last = 63 - __clzll(alive); jmax[b] = (last + 8) & ~7; }
    }
}

// ---------------------------------------------------------------------------
// K1: rational IoU max, TWO rois per thread (i0 and i0+HALF_): GT LDS reads
//     and loop overhead amortize over two independent accumulator chains.
//     Per-roi numerics identical to the proven R10/R11 kernel (Dekker exact
//     cross-product lex compare on (inter, s=area_a+ga); one IEEE divide).
// ---------------------------------------------------------------------------
__global__ void iou_kernel(const float* __restrict__ all_rois,
                           const float* __restrict__ gt_boxes,
                           const float4* __restrict__ gt4,
                           const float*  __restrict__ garea,
                           const int*    __restrict__ jmax,
                           const float*  __restrict__ u_perm,
                           unsigned*     __restrict__ packed,
                           int*          __restrict__ hist)
{
    __shared__ float4 sg[G_];
    __shared__ float  sa[G_];
    const int b   = blockIdx.y;
    const int tid = threadIdx.x;
    if (tid < G_) { sg[tid] = gt4[b * G_ + tid]; sa[tid] = garea[b * G_ + tid]; }
    __syncthreads();

    const int i0 = blockIdx.x * TPB_ + tid;
    if (i0 >= HALF_) return;
    const int i1 = i0 + HALF_;

    float ax1, ay1, ax2, ay2, bx1, by1, bx2, by2;
    {   // i0 < 32800 < N_ always
        const float* p = all_rois + ((size_t)b * N_ + i0) * 5;
        ax1 = p[1]; ay1 = p[2]; ax2 = p[3]; ay2 = p[4];
    }
    if (i1 < N_) {
        const float* p = all_rois + ((size_t)b * N_ + i1) * 5;
        bx1 = p[1]; by1 = p[2]; bx2 = p[3]; by2 = p[4];
    } else {
        const float* p = gt_boxes + (b * G_ + (i1 - N_)) * 6;
        bx1 = p[0]; by1 = p[1]; bx2 = p[2]; by2 = p[3];
    }
    float awA = ax2 - ax1 + 1.0f, ahA = ay2 - ay1 + 1.0f, areaA = awA * ahA;
    bool  azA = (awA == 1.0f) && (ahA == 1.0f);
    float awB = bx2 - bx1 + 1.0f, ahB = by2 - by1 + 1.0f, areaB = awB * ahB;
    bool  azB = (awB == 1.0f) && (ahB == 1.0f);

    const int jm = jmax[b];
    float ibA = 0.0f, sbA = 1.0f, ibB = 0.0f, sbB = 1.0f;
    for (int jj = 0; jj < jm; jj += 8) {
        #pragma unroll
        for (int kk = 0; kk < 8; ++kk) {
            const int j = jj + kk;
            const float4 g  = sg[j];
            const float  ga = sa[j];
            // roi A
            float iwA = fmaxf(fminf(ax2, g.z) - fmaxf(ax1, g.x) + 1.0f, 0.0f);
            float ihA = fmaxf(fminf(ay2, g.w) - fmaxf(ay1, g.y) + 1.0f, 0.0f);
            float inA = iwA * ihA;
            float sA  = areaA + ga;
            float h1 = inA * sbA, l1 = fmaf(inA, sbA, -h1);
            float h2 = ibA * sA,  l2 = fmaf(ibA, sA, -h2);
            if ((h1 > h2) || ((h1 == h2) && (l1 > l2))) { ibA = inA; sbA = sA; }
            // roi B
            float iwB = fmaxf(fminf(bx2, g.z) - fmaxf(bx1, g.x) + 1.0f, 0.0f);
            float ihB = fmaxf(fminf(by2, g.w) - fmaxf(by1, g.y) + 1.0f, 0.0f);
            float inB = iwB * ihB;
            float sB  = areaB + ga;
            float h3 = inB * sbB, l3 = fmaf(inB, sbB, -h3);
            float h4 = ibB * sB,  l4 = fmaf(ibB, sB, -h4);
            if ((h3 > h4) || ((h3 == h4) && (l3 > l4))) { ibB = inB; sbB = sB; }
        }
    }

    // finalize + classify + histogram, roi A then roi B
    {
        float best = ibA / (sbA - ibA);   // ref order: fl(fl(area_a+ga)-inter)
        if (azA) best = -1.0f;
        bool fg = best >= 0.7f, bg = best < 0.3f;
        unsigned pk = 0xFFFFFFFFu;
        if (fg || bg) {
            int cls = fg ? 0 : 1;
            float u = u_perm[(size_t)b * M_ + i0];
            int bucket = min(max((int)(u * (float)NB_), 0), NB_ - 1);
            pk = ((unsigned)cls << 16) | (unsigned)bucket;
            atomicAdd(&hist[(size_t)(b * 2 + cls) * NB_ + bucket], 1);
        }
        packed[(size_t)b * M_ + i0] = pk;
    }
    {
        float best = ibB / (sbB - ibB);
        if (azB) best = -1.0f;
        bool fg = best >= 0.7f, bg = best < 0.3f;
        unsigned pk = 0xFFFFFFFFu;
        if (fg || bg) {
            int cls = fg ? 0 : 1;
            float u = u_perm[(size_t)b * M_ + i1];
            int bucket = min(max((int)(u * (float)NB_), 0), NB_ - 1);
            pk = ((unsigned)cls << 16) | (unsigned)bucket;
            atomicAdd(&hist[(size_t)(b * 2 + cls) * NB_ + bucket], 1);
        }
        packed[(size_t)b * M_ + i1] = pk;
    }
}

// ---------------------------------------------------------------------------
// K2: fused tail, 16 blocks x 1024 threads (one block per batch; the entire
//     tail is batch-local so only block-level sync is needed):
//     T1 scan both rows concurrently (512 thr each, wave shfl scan), prefix
//        in place to global hist, coarse+cnt in LDS;
//     T2 flag: rank -> bucket (LDS coarse + global binsearch), LDS flag bits,
//        picks {start,cnt,r,is_fg} in LDS;
//     T3 scatter: grid-stride own batch's packed (uint4), LDS-flag filter,
//        destructive atomicAdd on prefix, write global buckets;
//     T4 sample: stable (u,idx) rank-select, gather, lazy argmax (ref
//        semantics) from the LDS GT tile; write outputs.
// ---------------------------------------------------------------------------
__global__ __launch_bounds__(1024) void tail_kernel(
    const float* __restrict__ all_rois,
    const float* __restrict__ gt_boxes,
    const float4* __restrict__ gt4,
    const float*  __restrict__ garea,
    const float* __restrict__ u_perm,
    const float* __restrict__ u_fg,
    const float* __restrict__ u_bg,
    const unsigned* __restrict__ packed,
    int*      __restrict__ hist,      // counts -> excl prefix -> destroyed
    int*      __restrict__ buckets,   // NROW*M
    float*    __restrict__ out)
{
    __shared__ float4   sg[G_];
    __shared__ float    sa[G_];
    __shared__ unsigned sflags[2 * FW_];   // 4 KB, this batch's two rows
    __shared__ int      scoarse[2][NCH_];
    __shared__ int      scnt[2];
    __shared__ int      swt[2][8], swb[2][8];
    __shared__ int4     spick[R_];

    const int bb  = blockIdx.x;       // batch
    const int tid = threadIdx.x;      // 0..1023
    const int rr  = tid >> 9;         // 0 = fg row, 1 = bg row
    const int t   = tid & 511;
    const int lane = tid & 63, w = (tid >> 6) & 7;

    sflags[tid] = 0;                  // 1024 == 2*FW_
    if (tid < G_) { sg[tid] = gt4[bb * G_ + tid]; sa[tid] = garea[bb * G_ + tid]; }

    // ---- T1: scan both rows concurrently ----
    const int row = bb * 2 + rr;
    int4* h4 = (int4*)(hist + (size_t)row * NB_ + t * 32);
    int v[32];
    #pragma unroll
    for (int q = 0; q < 8; ++q) {
        int4 x4 = h4[q];
        v[q*4] = x4.x; v[q*4+1] = x4.y; v[q*4+2] = x4.z; v[q*4+3] = x4.w;
    }
    int run = 0;
    #pragma unroll
    for (int q = 0; q < 32; ++q) { int x = v[q]; v[q] = run; run += x; }
    int x = run;                                   // wave inclusive scan
    #pragma unroll
    for (int d = 1; d < 64; d <<= 1) {
        int y = __shfl_up(x, d);
        if (lane >= d) x += y;
    }
    if (lane == 63) swt[rr][w] = x;
    __syncthreads();
    if ((tid & 511) == 0) {                        // tid 0 -> rr0, tid 512 -> rr1
        int a = 0;
        #pragma unroll
        for (int q = 0; q < 8; ++q) { swb[rr][q] = a; a += swt[rr][q]; }
        scnt[rr] = a;                              // row total
    }
    __syncthreads();
    const int incl  = swb[rr][w] + x;              // thread-inclusive
    const int texcl = incl - run;                  // thread-exclusive base
    #pragma unroll
    for (int q = 0; q < 8; ++q) {
        h4[q] = make_int4(v[q*4] + texcl, v[q*4+1] + texcl,
                          v[q*4+2] + texcl, v[q*4+3] + texcl);
    }
    if ((t & 15) == 15) scoarse[rr][t >> 4] = incl;  // 512-bin chunk inclusives
    __threadfence();   // drain prefix stores to L2 (same block reads them next)
    __syncthreads();

    // ---- T2: flag + picks (threads 0..127) ----
    if (tid < R_) {
        const int pos = tid;
        const int fgn = scnt[0], bgn = scnt[1];
        const bool both    = (fgn > 0) && (bgn > 0);
        const bool only_fg = (fgn > 0) && (bgn == 0);
        const int fg_this  = both ? min(FGP, fgn) : (only_fg ? R_ : 0);
        const bool is_fg   = pos < fg_this;
        int cls, rank, cnum;
        if (is_fg) {
            cls = 0; cnum = fgn;
            if (only_fg) {
                float uf = u_fg[bb * R_ + pos];
                int kk = (int)(uf * (float)fgn);       // trunc toward zero
                rank = min(max(kk, 0), max(fgn - 1, 0));
            } else {
                rank = pos;
            }
        } else {
            cls = 1; cnum = bgn;
            float ubv = u_bg[bb * R_ + pos];
            int kk = (int)(ubv * (float)bgn);
            rank = min(max(kk, 0), max(bgn - 1, 0));
        }
        int4 p4 = make_int4(0, 0, 0, is_fg ? 1 : 0);   // cnum==0 sentinel
        if (cnum > 0) {
            const int* sce = scoarse[cls];
            int c = 0;                     // first chunk with incl > rank
            while (c < NCH_ - 1 && sce[c] <= rank) ++c;
            const int* Er = hist + (size_t)(bb * 2 + cls) * NB_;
            int lo = c * CHUNK_, hi = c * CHUNK_ + CHUNK_ - 1;
            while (lo < hi) {              // max j with Er[j] <= rank
                int mid = (lo + hi + 1) >> 1;
                if (Er[mid] <= rank) lo = mid; else hi = mid - 1;
            }
            const int start = Er[lo];
            const int next  = (lo < NB_ - 1) ? Er[lo + 1] : cnum;
            atomicOr(&sflags[cls * FW_ + (lo >> 5)], 1u << (lo & 31));
            p4 = make_int4(start, next - start, rank - start, is_fg ? 1 : 0);
        }
        spick[pos] = p4;
    }
    __syncthreads();

    // ---- T3: scatter flagged-bucket members of this batch ----
    {
        const uint4* pb = (const uint4*)(packed + (size_t)bb * M_);
        for (int it2 = 0; it2 < 17; ++it2) {
            const int i4 = it2 * 1024 + tid;
            if (i4 >= M_ / 4) break;
            const uint4 pv = pb[i4];
            const unsigned arr[4] = { pv.x, pv.y, pv.z, pv.w };
            #pragma unroll
            for (int k = 0; k < 4; ++k) {
                unsigned pk = arr[k];
                if (pk == 0xFFFFFFFFu) continue;
                const int cls = (int)(pk >> 16);
                const int bucket = (int)(pk & 0xFFFFu);
                unsigned wd = sflags[cls * FW_ + (bucket >> 5)];
                if (!(wd & (1u << (bucket & 31)))) continue;
                int pp = atomicAdd(&hist[(size_t)(bb * 2 + cls) * NB_ + bucket], 1);
                buckets[(size_t)(bb * 2 + cls) * M_ + pp] = i4 * 4 + k;
            }
        }
    }
    __threadfence();
    __syncthreads();

    // ---- T4: selection + gather + lazy argmax (threads 0..127) ----
    if (tid < R_) {
        const int pos = tid;
        const int4 p4 = spick[pos];
        const bool is_fg = p4.w != 0;
        const int  cls   = is_fg ? 0 : 1;
        int keep = 0;                  // cnum==0 edge: argsort(all 2.0)[0] == 0
        if (p4.y > 0) {
            const int*   be = buckets + (size_t)(bb * 2 + cls) * M_ + p4.x;
            const float* up = u_perm + (size_t)bb * M_;
            const int cnt2 = p4.y, r = p4.z;
            for (int t2 = 0; t2 < cnt2; ++t2) {   // r-th smallest by (u, idx)
                int it2 = be[t2]; float ut = up[it2];
                int rk = 0;
                for (int s2 = 0; s2 < cnt2; ++s2) {
                    if (s2 == t2) continue;
                    int is2 = be[s2]; float us = up[is2];
                    if (us < ut || (us == ut && is2 < it2)) rk++;
                }
                if (rk == r) { keep = it2; break; }
            }
        }
        float ox1, oy1, ox2, oy2;
        if (keep < N_) {
            const float* p = all_rois + ((size_t)bb * N_ + keep) * 5;
            ox1 = p[1]; oy1 = p[2]; ox2 = p[3]; oy2 = p[4];
        } else {
            const float* p = gt_boxes + (bb * G_ + (keep - N_)) * 6;
            ox1 = p[0]; oy1 = p[1]; ox2 = p[2]; oy2 = p[3];
        }
        float* ro = out + ((size_t)bb * R_ + pos) * 5;
        ro[0] = (float)bb; ro[1] = ox1; ro[2] = oy1; ro[3] = ox2; ro[4] = oy2;

        float lab = 0.0f, tidv = -1.0f;
        if (is_fg) {
            float aw = ox2 - ox1 + 1.0f, ah = oy2 - oy1 + 1.0f;
            float area_a = aw * ah;
            float bestv = -1e30f;
            int   bi    = 0;
            for (int j = 0; j < G_; ++j) {
                const float4 g  = sg[j];
                const float  ga = sa[j];
                float iw  = fmaxf(fminf(ox2, g.z) - fmaxf(ox1, g.x) + 1.0f, 0.0f);
                float ih2 = fmaxf(fminf(oy2, g.w) - fmaxf(oy1, g.y) + 1.0f, 0.0f);
                float inter = iw * ih2;
                float ov = inter / (area_a + ga - inter);   // IEEE div, ref order
                if (ov > bestv) { bestv = ov; bi = j; }     // first-max
            }
            lab  = gt_boxes[(bb * G_ + bi) * 6 + 4];
            tidv = gt_boxes[(bb * G_ + bi) * 6 + 5];
        }
        out[(size_t)B_ * R_ * 5 + bb * R_ + pos] = lab;
        out[(size_t)B_ * R_ * 5 + (size_t)B_ * R_ + bb * R_ + pos] = tidv;
    }
}

// ---------------------------------------------------------------------------
extern "C" void kernel_launch(void* const* d_in, const int* in_sizes, int n_in,
                              void* d_out, int out_size, void* d_ws, size_t ws_size,
                              hipStream_t stream)
{
    const float* all_rois = (const float*)d_in[0];
    const float* gt_boxes = (const float*)d_in[1];
    const float* u_perm   = (const float*)d_in[2];
    const float* u_fg     = (const float*)d_in[3];
    const float* u_bg     = (const float*)d_in[4];
    float* out = (float*)d_out;

    // workspace layout (4B elems); ~15 MB. packed/gt4 16B-aligned.
    int*      hist    = (int*)d_ws;                               // NROW*NB (2MB)
    unsigned* packed  = (unsigned*)(hist + (size_t)NROW_ * NB_);  // B*M
    int*      buckets = (int*)(packed + (size_t)B_ * M_);         // NROW*M
    float4*   gt4     = (float4*)(buckets + (size_t)NROW_ * M_);  // B*G
    float*    garea   = (float*)(gt4 + B_ * G_);                  // B*G
    int*      jmax    = (int*)(garea + B_ * G_);                  // B

    prep_kernel<<<512, TPB_, 0, stream>>>(gt_boxes, hist, gt4, garea, jmax);

    dim3 grid1((HALF_ + TPB_ - 1) / TPB_, B_);   // 129 x 16
    iou_kernel<<<grid1, TPB_, 0, stream>>>(all_rois, gt_boxes, gt4, garea, jmax,
                                           u_perm, packed, hist);
    tail_kernel<<<B_, 1024, 0, stream>>>(all_rois, gt_boxes, gt4, garea,
                                         u_perm, u_fg, u_bg, packed,
                                         hist, buckets, out);
}

// Round 14
// 111.526 us; speedup vs baseline: 1.1328x; 1.1328x over previous
//
#include <hip/hip_runtime.h>

// Problem constants (match reference)
#define B_   16
#define N_   65536
#define G_   64
#define M_   (N_ + G_)       // 65600 rois per batch
#define Q_   16400           // M_/4: each iou thread handles i, i+Q, i+2Q, i+3Q
#define R_   128             // ROIS_PER_IMAGE
#define FGP  32              // FG_PER_IMAGE
#define NB_  16384           // buckets over u_perm in [0,1): lambda ~= 3.7 bg
#define NCH_ 32              // coarse chunks per row
#define CHUNK_ (NB_ / NCH_)  // 512
#define NROW_ 32             // (batch, class) rows
#define FW_  (NB_ / 32)      // flag words per row = 512
#define TPB_  256

// ---------------------------------------------------------------------------
// In-block GT tile build: 64 lanes (wave 0) read gt_boxes, poison gt_zero
// rows, compute area, ballot-derive jmax. Identical values to the proven
// prep_kernel -- just computed redundantly per block (64 lanes, ~10 ops).
// ---------------------------------------------------------------------------
__device__ __forceinline__ void build_gt_tile(const float* __restrict__ gt_boxes,
                                              int b, int tid,
                                              float4* sg, float* sa, int* sjm)
{
    if (tid < G_) {
        const float* g = gt_boxes + (b * G_ + tid) * 6;
        float x1 = g[0], y1 = g[1], x2 = g[2], y2 = g[3];
        float gw = x2 - x1 + 1.0f, gh = y2 - y1 + 1.0f;
        bool gz = (gw == 1.0f) && (gh == 1.0f);
        sg[tid] = gz ? make_float4(3.0e8f, 3.0e8f, -3.0e8f, -3.0e8f)
                     : make_float4(x1, y1, x2, y2);
        sa[tid] = gw * gh;                        // == 1.0 for gz rows
        unsigned long long alive = __ballot(!gz); // wave 0 only: lane == j
        if (tid == 0) { int last = 63 - __clzll(alive); *sjm = (last + 8) & ~7; }
    }
    __syncthreads();
}

// ---------------------------------------------------------------------------
// K1: rational IoU max, FOUR rois per thread (i, i+Q, i+2Q, i+3Q): GT LDS
//     reads and loop overhead amortize over 4 independent compare chains.
//     Per-roi numerics identical to the proven R10-R13 kernels (Dekker exact
//     cross-product lex compare on (inter, s=area_a+ga); one IEEE divide).
// ---------------------------------------------------------------------------
__global__ __launch_bounds__(TPB_, 4) void iou_kernel(
    const float* __restrict__ all_rois,
    const float* __restrict__ gt_boxes,
    const float* __restrict__ u_perm,
    unsigned*    __restrict__ packed,
    int*         __restrict__ hist)
{
    __shared__ float4 sg[G_];
    __shared__ float  sa[G_];
    __shared__ int    sjm;
    const int b   = blockIdx.y;
    const int tid = threadIdx.x;
    build_gt_tile(gt_boxes, b, tid, sg, sa, &sjm);

    const int i0 = blockIdx.x * TPB_ + tid;
    if (i0 >= Q_) return;
    const int jm = sjm;

    float X1[4], Y1[4], X2[4], Y2[4], AREA[4], IB[4], SB[4];
    bool  AZ[4];
    #pragma unroll
    for (int r = 0; r < 4; ++r) {
        const int i = i0 + r * Q_;
        float x1, y1, x2, y2;
        if (i < N_) {
            const float* p = all_rois + ((size_t)b * N_ + i) * 5;
            x1 = p[1]; y1 = p[2]; x2 = p[3]; y2 = p[4];
        } else {
            const float* p = gt_boxes + (b * G_ + (i - N_)) * 6;
            x1 = p[0]; y1 = p[1]; x2 = p[2]; y2 = p[3];
        }
        float aw = x2 - x1 + 1.0f, ah = y2 - y1 + 1.0f;
        X1[r] = x1; Y1[r] = y1; X2[r] = x2; Y2[r] = y2;
        AREA[r] = aw * ah;
        AZ[r] = (aw == 1.0f) && (ah == 1.0f);
        IB[r] = 0.0f; SB[r] = 1.0f;              // rational best t = 0/1
    }

    for (int jj = 0; jj < jm; jj += 4) {
        #pragma unroll
        for (int kk = 0; kk < 4; ++kk) {
            const int j = jj + kk;
            const float4 g  = sg[j];
            const float  ga = sa[j];
            #pragma unroll
            for (int r = 0; r < 4; ++r) {
                float iw = fmaxf(fminf(X2[r], g.z) - fmaxf(X1[r], g.x) + 1.0f, 0.0f);
                float ih = fmaxf(fminf(Y2[r], g.w) - fmaxf(Y1[r], g.y) + 1.0f, 0.0f);
                float inter = iw * ih;
                float s     = AREA[r] + ga;
                float h1 = inter * SB[r], l1 = fmaf(inter, SB[r], -h1);
                float h2 = IB[r] * s,     l2 = fmaf(IB[r], s, -h2);
                if ((h1 > h2) || ((h1 == h2) && (l1 > l2))) { IB[r] = inter; SB[r] = s; }
            }
        }
    }

    #pragma unroll
    for (int r = 0; r < 4; ++r) {
        const int i = i0 + r * Q_;
        float best = IB[r] / (SB[r] - IB[r]);  // ref order: fl(fl(area+ga)-inter)
        if (AZ[r]) best = -1.0f;
        bool fg = best >= 0.7f, bg = best < 0.3f;  // bg == ((mo<.3)&(mo>=0))|(mo<0)
        unsigned pk = 0xFFFFFFFFu;
        if (fg || bg) {
            int cls = fg ? 0 : 1;
            float u = u_perm[(size_t)b * M_ + i];
            int bucket = min(max((int)(u * (float)NB_), 0), NB_ - 1);
            pk = ((unsigned)cls << 16) | (unsigned)bucket;
            atomicAdd(&hist[(size_t)(b * 2 + cls) * NB_ + bucket], 1);
        }
        packed[(size_t)b * M_ + i] = pk;
    }
}

// ---------------------------------------------------------------------------
// K2: 16 blocks x 512 threads (structure proven R9/R12). Each block
//     exclusive-scans BOTH rows of its batch in place (wave shfl scan;
//     coarse+cnt in LDS), then flags: rank -> bucket via LDS coarse walk +
//     global binsearch; flag bits accumulated in LDS and FULLY written to
//     global (so flags needs no pre-zeroing); picks {start,cnt,r,is_fg} out.
// ---------------------------------------------------------------------------
__global__ __launch_bounds__(512) void scanflag_kernel(
    int*      __restrict__ hist,     // counts -> exclusive prefix (in place)
    unsigned* __restrict__ flags,
    const float* __restrict__ u_fg,
    const float* __restrict__ u_bg,
    int4*     __restrict__ pick)
{
    __shared__ unsigned sflags[2 * FW_];   // 4 KB
    __shared__ int scoarse[2][NCH_];
    __shared__ int scnt[2];
    __shared__ int swt[2][8], swb[2][8];
    const int bb  = blockIdx.x;       // batch
    const int tid = threadIdx.x;      // 512
    const int lane = tid & 63, w = tid >> 6;

    sflags[tid] = 0; sflags[tid + 512] = 0;

    for (int rr = 0; rr < 2; ++rr) {
        const int row = bb * 2 + rr;
        int4* h4 = (int4*)(hist + (size_t)row * NB_ + tid * 32);
        int v[32];
        #pragma unroll
        for (int q = 0; q < 8; ++q) {
            int4 x4 = h4[q];
            v[q*4] = x4.x; v[q*4+1] = x4.y; v[q*4+2] = x4.z; v[q*4+3] = x4.w;
        }
        int run = 0;
        #pragma unroll
        for (int q = 0; q < 32; ++q) { int x = v[q]; v[q] = run; run += x; }
        int x = run;                                   // wave inclusive scan
        #pragma unroll
        for (int d = 1; d < 64; d <<= 1) {
            int y = __shfl_up(x, d);
            if (lane >= d) x += y;
        }
        if (lane == 63) swt[rr][w] = x;
        __syncthreads();
        if (tid == 0) {
            int a = 0;
            #pragma unroll
            for (int q = 0; q < 8; ++q) { swb[rr][q] = a; a += swt[rr][q]; }
        }
        __syncthreads();
        const int incl  = swb[rr][w] + x;              // thread-inclusive
        const int texcl = incl - run;                  // thread-exclusive base
        #pragma unroll
        for (int q = 0; q < 8; ++q) {
            h4[q] = make_int4(v[q*4] + texcl, v[q*4+1] + texcl,
                              v[q*4+2] + texcl, v[q*4+3] + texcl);
        }
        if ((tid & 15) == 15) scoarse[rr][tid >> 4] = incl;  // 512-bin chunks
        if (tid == 511) scnt[rr] = incl;
    }
    __syncthreads();   // prefix writes + scoarse/scnt visible block-wide

    if (tid < R_) {
        const int pos = tid;
        const int fgn = scnt[0], bgn = scnt[1];
        const bool both    = (fgn > 0) && (bgn > 0);
        const bool only_fg = (fgn > 0) && (bgn == 0);
        const int fg_this  = both ? min(FGP, fgn) : (only_fg ? R_ : 0);
        const bool is_fg   = pos < fg_this;
        int cls, rank, cnum;
        if (is_fg) {
            cls = 0; cnum = fgn;
            if (only_fg) {
                float uf = u_fg[bb * R_ + pos];
                int kk = (int)(uf * (float)fgn);       // trunc toward zero
                rank = min(max(kk, 0), max(fgn - 1, 0));
            } else {
                rank = pos;
            }
        } else {
            cls = 1; cnum = bgn;
            float ubv = u_bg[bb * R_ + pos];
            int kk = (int)(ubv * (float)bgn);
            rank = min(max(kk, 0), max(bgn - 1, 0));
        }
        int4 p4 = make_int4(0, 0, 0, is_fg ? 1 : 0);   // cnum==0 sentinel
        if (cnum > 0) {
            const int* sce = scoarse[cls];
            int c = 0;                     // first chunk with incl > rank
            while (c < NCH_ - 1 && sce[c] <= rank) ++c;
            const int* Er = hist + (size_t)(bb * 2 + cls) * NB_;
            int lo = c * CHUNK_, hi = c * CHUNK_ + CHUNK_ - 1;
            while (lo < hi) {              // max j with Er[j] <= rank
                int mid = (lo + hi + 1) >> 1;
                if (Er[mid] <= rank) lo = mid; else hi = mid - 1;
            }
            const int start = Er[lo];
            const int next  = (lo < NB_ - 1) ? Er[lo + 1] : cnum;
            atomicOr(&sflags[cls * FW_ + (lo >> 5)], 1u << (lo & 31));
            p4 = make_int4(start, next - start, rank - start, is_fg ? 1 : 0);
        }
        pick[bb * R_ + pos] = p4;
    }
    __syncthreads();
    flags[bb * 2 * FW_ + tid]       = sflags[tid];       // full write: no
    flags[bb * 2 * FW_ + tid + 512] = sflags[tid + 512]; // pre-zero needed
}

// ---------------------------------------------------------------------------
// K3: scatter ONLY flagged-bucket members; uint4 packed reads (4 rois/thread).
//     Destructive atomicAdd on the prefix is fine: picks carry start/cnt.
// ---------------------------------------------------------------------------
__global__ void scatter_kernel(const unsigned* __restrict__ packed,
                               const unsigned* __restrict__ flags,
                               int*            __restrict__ E,      // hist prefix
                               int*            __restrict__ buckets)
{
    const int b  = blockIdx.y;
    const int i4 = blockIdx.x * blockDim.x + threadIdx.x;
    if (i4 >= M_ / 4) return;
    const uint4 p = ((const uint4*)(packed + (size_t)b * M_))[i4];
    const unsigned pks[4] = { p.x, p.y, p.z, p.w };
    #pragma unroll
    for (int k = 0; k < 4; ++k) {
        unsigned pk = pks[k];
        if (pk == 0xFFFFFFFFu) continue;
        const int cls = (int)(pk >> 16);
        const int bucket = (int)(pk & 0xFFFFu);
        const int row = b * 2 + cls;
        unsigned w = flags[row * FW_ + (bucket >> 5)];     // 64KB table: L2-hot
        if (!(w & (1u << (bucket & 31)))) continue;
        int pp = atomicAdd(&E[(size_t)row * NB_ + bucket], 1);
        buckets[(size_t)row * M_ + pp] = i4 * 4 + k;
    }
}

// ---------------------------------------------------------------------------
// K4: stable (u, idx) rank-selection among bucket members, gather outputs,
//     lazy argmax (reference divide semantics) for picked fg rois only.
//     GT tile rebuilt in-block from gt_boxes.
// ---------------------------------------------------------------------------
__global__ void sample_kernel(const float* __restrict__ all_rois,
                              const float* __restrict__ gt_boxes,
                              const float* __restrict__ u_perm,
                              const int4* __restrict__ pick,
                              const int*  __restrict__ buckets,
                              float*      __restrict__ out)
{
    __shared__ float4 sg[G_];
    __shared__ float  sa[G_];
    __shared__ int    sjm;           // unused here, needed by builder signature
    const int b   = blockIdx.x;
    const int pos = threadIdx.x;     // 128
    build_gt_tile(gt_boxes, b, pos, sg, sa, &sjm);

    const int4 pk = pick[b * R_ + pos];
    const bool is_fg = pk.w != 0;
    const int  cls   = is_fg ? 0 : 1;

    int keep = 0;                  // cnum==0 edge: argsort(all 2.0)[0] == 0
    if (pk.y > 0) {
        const int*   be = buckets + (size_t)(b * 2 + cls) * M_ + pk.x;
        const float* up = u_perm + (size_t)b * M_;
        const int cnt2 = pk.y, r = pk.z;
        for (int t2 = 0; t2 < cnt2; ++t2) {   // r-th smallest by (u, idx)
            int it = be[t2]; float ut = up[it];
            int rk = 0;
            for (int s2 = 0; s2 < cnt2; ++s2) {
                if (s2 == t2) continue;
                int is2 = be[s2]; float us = up[is2];
                if (us < ut || (us == ut && is2 < it)) rk++;
            }
            if (rk == r) { keep = it; break; }
        }
    }

    float ox1, oy1, ox2, oy2;
    if (keep < N_) {
        const float* p = all_rois + ((size_t)b * N_ + keep) * 5;
        ox1 = p[1]; oy1 = p[2]; ox2 = p[3]; oy2 = p[4];
    } else {
        const float* p = gt_boxes + (b * G_ + (keep - N_)) * 6;
        ox1 = p[0]; oy1 = p[1]; ox2 = p[2]; oy2 = p[3];
    }
    float* ro = out + ((size_t)b * R_ + pos) * 5;
    ro[0] = (float)b; ro[1] = ox1; ro[2] = oy1; ro[3] = ox2; ro[4] = oy2;

    float lab = 0.0f, tidv = -1.0f;
    if (is_fg) {
        float aw = ox2 - ox1 + 1.0f, ah = oy2 - oy1 + 1.0f;
        float area_a = aw * ah;
        float bestv = -1e30f;
        int   bi    = 0;
        for (int j = 0; j < G_; ++j) {
            const float4 g  = sg[j];
            const float  ga = sa[j];
            float iw  = fmaxf(fminf(ox2, g.z) - fmaxf(ox1, g.x) + 1.0f, 0.0f);
            float ih2 = fmaxf(fminf(oy2, g.w) - fmaxf(oy1, g.y) + 1.0f, 0.0f);
            float inter = iw * ih2;
            float ov = inter / (area_a + ga - inter);   // IEEE div, ref order
            if (ov > bestv) { bestv = ov; bi = j; }     // first-max
        }
        lab  = gt_boxes[(b * G_ + bi) * 6 + 4];
        tidv = gt_boxes[(b * G_ + bi) * 6 + 5];
    }
    out[(size_t)B_ * R_ * 5 + b * R_ + pos] = lab;
    out[(size_t)B_ * R_ * 5 + (size_t)B_ * R_ + b * R_ + pos] = tidv;
}

// ---------------------------------------------------------------------------
extern "C" void kernel_launch(void* const* d_in, const int* in_sizes, int n_in,
                              void* d_out, int out_size, void* d_ws, size_t ws_size,
                              hipStream_t stream)
{
    const float* all_rois = (const float*)d_in[0];
    const float* gt_boxes = (const float*)d_in[1];
    const float* u_perm   = (const float*)d_in[2];
    const float* u_fg     = (const float*)d_in[3];
    const float* u_bg     = (const float*)d_in[4];
    float* out = (float*)d_out;

    // workspace layout (4B elems); ~14.7 MB. 16B alignment throughout.
    int*      hist    = (int*)d_ws;                               // NROW*NB (2MB)
    unsigned* flags   = (unsigned*)(hist + (size_t)NROW_ * NB_);  // NROW*FW (64KB)
    int4*     pick    = (int4*)(flags + NROW_ * FW_);             // B*R int4
    unsigned* packed  = (unsigned*)(pick + B_ * R_);              // B*M (4.2MB)
    int*      buckets = (int*)(packed + (size_t)B_ * M_);         // NROW*M (8.4MB)

    hipMemsetAsync(hist, 0, (size_t)NROW_ * NB_ * sizeof(int), stream);

    dim3 grid1((Q_ + TPB_ - 1) / TPB_, B_);      // 65 x 16
    iou_kernel<<<grid1, TPB_, 0, stream>>>(all_rois, gt_boxes, u_perm, packed, hist);
    scanflag_kernel<<<B_, 512, 0, stream>>>(hist, flags, u_fg, u_bg, pick);

    dim3 grid3((M_ / 4 + TPB_ - 1) / TPB_, B_);
    scatter_kernel<<<grid3, TPB_, 0, stream>>>(packed, flags, hist, buckets);
    sample_kernel<<<B_, R_, 0, stream>>>(all_rois, gt_boxes, u_perm, pick, buckets, out);
}